// Round 1
// baseline (743.022 us; speedup 1.0000x reference)
//
#include <hip/hip_runtime.h>
#include <hip/hip_bf16.h>

typedef __bf16 bf16x8 __attribute__((ext_vector_type(8)));
typedef __bf16 bf16x4 __attribute__((ext_vector_type(4)));
typedef float f32x4 __attribute__((ext_vector_type(4)));

#define BM 128
#define BN 128
#define BK 32

__device__ __forceinline__ void gload16(const __bf16* g, __bf16* l) {
    __builtin_amdgcn_global_load_lds((const __attribute__((address_space(1))) void*)g,
                                     (__attribute__((address_space(3))) void*)l, 16, 0, 0);
}

__device__ __forceinline__ float gelu_f(float v) {
    float z = 0.7978845608028654f * (v + 0.044715f * v * v * v);
    float e = __expf(2.f * z);
    return 0.5f * v * (2.f - 2.f / (e + 1.f));  // 0.5*v*(1+tanh(z)), overflow-safe
}

// ---------------- diagnostic fill (fp32 out) ----------------
__global__ __launch_bounds__(256) void diag_kernel(float* out, int n, float v) {
    int i = blockIdx.x * 256 + threadIdx.x;
    if (i < n) out[i] = v;
}

// ---------------- fused fp32->bf16 convert + transpose: in[K,N] -> out[N,K] ----------------
__global__ __launch_bounds__(256) void cvtT_kernel(
    const float* __restrict__ in, __bf16* __restrict__ out, int K, int N)
{
    __shared__ __bf16 tile[32][33];
    int bx = blockIdx.x * 32, by = blockIdx.y * 32;  // bx: n, by: k
    int tx = threadIdx.x & 31, ty = threadIdx.x >> 5;  // 32 x 8
#pragma unroll
    for (int i = 0; i < 32; i += 8)
        tile[ty + i][tx] = (__bf16)in[(size_t)(by + ty + i) * N + bx + tx];
    __syncthreads();
#pragma unroll
    for (int i = 0; i < 32; i += 8)
        out[(size_t)(bx + ty + i) * K + by + tx] = tile[tx][ty + i];
}

// ---------------- LayerNorm: fp32 in, bf16 out; one block per row of 1024 ----------------
// Optional fused side-output: out2[row] = x[row] + bias2 (fp32) — pre-inits the
// split-K atomic accumulator for the following GEMM without an extra x1 read pass.
__global__ __launch_bounds__(256) void ln_kernel(
    const float* __restrict__ x, const float* __restrict__ g,
    const float* __restrict__ bta, __bf16* __restrict__ out,
    const float* __restrict__ bias2, float* __restrict__ out2)
{
    const int row = blockIdx.x, t = threadIdx.x;
    const float* xr = x + (size_t)row * 1024;
    float4 xv = ((const float4*)xr)[t];
    float f[4] = {xv.x, xv.y, xv.z, xv.w};
    float s = f[0] + f[1] + f[2] + f[3];
    float ss = f[0]*f[0] + f[1]*f[1] + f[2]*f[2] + f[3]*f[3];
#pragma unroll
    for (int off = 32; off; off >>= 1) {
        s  += __shfl_xor(s, off, 64);
        ss += __shfl_xor(ss, off, 64);
    }
    __shared__ float red[8];
    int lane = t & 63, w = t >> 6;
    if (lane == 0) { red[w] = s; red[4 + w] = ss; }
    __syncthreads();
    s  = red[0] + red[1] + red[2] + red[3];
    ss = red[4] + red[5] + red[6] + red[7];
    float mu = s * (1.f / 1024.f);
    float var = ss * (1.f / 1024.f) - mu * mu;
    float rstd = rsqrtf(fmaxf(var, 0.f) + 1e-5f);
    float4 gv = ((const float4*)g)[t];
    float4 bv = ((const float4*)bta)[t];
    bf16x4 ov;
    ov[0] = (__bf16)((f[0] - mu) * rstd * gv.x + bv.x);
    ov[1] = (__bf16)((f[1] - mu) * rstd * gv.y + bv.y);
    ov[2] = (__bf16)((f[2] - mu) * rstd * gv.z + bv.z);
    ov[3] = (__bf16)((f[3] - mu) * rstd * gv.w + bv.w);
    ((bf16x4*)(out + (size_t)row * 1024))[t] = ov;
    if (out2) {
        float4 b2 = ((const float4*)bias2)[t];
        float4 o2 = {f[0] + b2.x, f[1] + b2.y, f[2] + b2.z, f[3] + b2.w};
        ((float4*)(out2 + (size_t)row * 1024))[t] = o2;
    }
}

// ---------------- GEMM 128x128 (m97 + dbuf 2-phase): C = A @ BT^T + epilogue ----------------
// EPI: 0 bias, 1 bias+res(f32), 2 bias+gelu, 3 split-K atomicAdd (raw acc, out pre-inited)
// NSPLIT>1: blockIdx.z selects K-slice (split-K to raise blocks/CU for skinny-N shapes).
template <int EPI, bool OUT32, int NSPLIT>
__global__ __launch_bounds__(256, 4) void gemm_bt_kernel(
    const __bf16* __restrict__ A, const __bf16* __restrict__ BT,
    const float* __restrict__ bias, const float* __restrict__ res,
    void* __restrict__ Cp, int M, int N, int K, int lda, int ldb)
{
    __shared__ __align__(16) __bf16 lA[2][BM * BK];  // phys = kc*1024 + row*8 + j
    __shared__ __align__(16) __bf16 lB[2][BN * BK];
    const int t = threadIdx.x;
    const int lane = t & 63;
    const int wave = t >> 6;
    const int wm = wave >> 1, wn = wave & 1;
    const int q4 = lane >> 4, r16 = lane & 15;
    const int bm = blockIdx.y * BM, bn = blockIdx.x * BN;
    const int Klen = K / NSPLIT;
    const int koff = (NSPLIT > 1) ? (int)blockIdx.z * Klen : 0;

    const int srow = t & 127;
    const int skc = t >> 7;
    const __bf16* ga0 = A + (size_t)(bm + srow) * lda + koff + skc * 8;
    const __bf16* ga1 = ga0 + 16;
    const __bf16* gb0 = BT + (size_t)(bn + srow) * ldb + koff + skc * 8;
    const __bf16* gb1 = gb0 + 16;

    f32x4 acc[4][4];
    f32x4 zero4 = {0.f, 0.f, 0.f, 0.f};
#pragma unroll
    for (int mi = 0; mi < 4; ++mi)
#pragma unroll
        for (int ni = 0; ni < 4; ++ni) acc[mi][ni] = zero4;

    // prologue: stage tile 0 into buf 0
    gload16(ga0, &lA[0][t * 8]);
    gload16(ga1, &lA[0][t * 8 + 2048]);
    gload16(gb0, &lB[0][t * 8]);
    gload16(gb1, &lB[0][t * 8 + 2048]);
    ga0 += BK; ga1 += BK; gb0 += BK; gb1 += BK;
    __syncthreads();  // drains vmcnt, tile 0 visible

    const int nk = Klen / BK;
    int cur = 0;
    for (int it = 0; it < nk; ++it) {
        if (it + 1 < nk) {  // issue next tile's loads BEFORE computing current
            gload16(ga0, &lA[cur ^ 1][t * 8]);
            gload16(ga1, &lA[cur ^ 1][t * 8 + 2048]);
            gload16(gb0, &lB[cur ^ 1][t * 8]);
            gload16(gb1, &lB[cur ^ 1][t * 8 + 2048]);
            ga0 += BK; ga1 += BK; gb0 += BK; gb1 += BK;
        }
        bf16x8 af[4], bfr[4];
#pragma unroll
        for (int i = 0; i < 4; ++i)
            af[i] = *(const bf16x8*)&lA[cur][q4 * 1024 + (wm * 64 + i * 16 + r16) * 8];
#pragma unroll
        for (int i = 0; i < 4; ++i)
            bfr[i] = *(const bf16x8*)&lB[cur][q4 * 1024 + (wn * 64 + i * 16 + r16) * 8];
#pragma unroll
        for (int mi = 0; mi < 4; ++mi)
#pragma unroll
            for (int ni = 0; ni < 4; ++ni)
                acc[mi][ni] = __builtin_amdgcn_mfma_f32_16x16x32_bf16(
                    af[mi], bfr[ni], acc[mi][ni], 0, 0, 0);
        if (it + 1 < nk) __syncthreads();  // next tile staged + cur reads done
        cur ^= 1;
    }

#pragma unroll
    for (int mi = 0; mi < 4; ++mi) {
#pragma unroll
        for (int ni = 0; ni < 4; ++ni) {
#pragma unroll
            for (int i = 0; i < 4; ++i) {
                int r = bm + wm * 64 + mi * 16 + q4 * 4 + i;
                int c = bn + wn * 64 + ni * 16 + r16;
                if (EPI == 3) {
                    atomicAdd((float*)Cp + (size_t)r * N + c, acc[mi][ni][i]);
                } else {
                    float v = acc[mi][ni][i] + bias[c];
                    if (EPI == 1) v += res[(size_t)r * N + c];
                    if (EPI == 2) v = gelu_f(v);
                    if (OUT32) ((float*)Cp)[(size_t)r * N + c] = v;
                    else       ((__bf16*)Cp)[(size_t)r * N + c] = (__bf16)v;
                }
            }
        }
    }
}

// ---------------- GEMM 128x256 wide (dbuf 2-phase): for N-fat layers (qkv, fc) ----------------
template <int EPI, bool OUT32>
__global__ __launch_bounds__(256, 2) void gemm_bt_wide_kernel(
    const __bf16* __restrict__ A, const __bf16* __restrict__ BT,
    const float* __restrict__ bias, const float* __restrict__ res,
    void* __restrict__ Cp, int M, int N, int K)
{
    __shared__ __align__(16) __bf16 lA[2][128 * BK];  // phys = kc*1024 + row*8 + j
    __shared__ __align__(16) __bf16 lB[2][256 * BK];  // phys = kc*2048 + row*8 + j
    const int t = threadIdx.x;
    const int lane = t & 63;
    const int wave = t >> 6;
    const int wm = wave >> 1, wn = wave & 1;
    const int q4 = lane >> 4, r16 = lane & 15;
    const int bm = blockIdx.y * 128, bn = blockIdx.x * 256;

    const int srow = t & 127;
    const int skc = t >> 7;
    const __bf16* ga0 = A + (size_t)(bm + srow) * K + skc * 8;
    const __bf16* ga1 = ga0 + 16;
    const __bf16* gb  = BT + (size_t)(bn + t) * K;

    f32x4 acc[4][8];
    f32x4 zero4 = {0.f, 0.f, 0.f, 0.f};
#pragma unroll
    for (int mi = 0; mi < 4; ++mi)
#pragma unroll
        for (int ni = 0; ni < 8; ++ni) acc[mi][ni] = zero4;

    // prologue: stage tile 0 into buf 0
    gload16(ga0, &lA[0][t * 8]);
    gload16(ga1, &lA[0][t * 8 + 2048]);
#pragma unroll
    for (int c = 0; c < 4; ++c)
        gload16(gb + c * 8, &lB[0][c * 2048 + t * 8]);
    ga0 += BK; ga1 += BK; gb += BK;
    __syncthreads();

    const int nk = K / BK;
    int cur = 0;
    for (int it = 0; it < nk; ++it) {
        if (it + 1 < nk) {
            gload16(ga0, &lA[cur ^ 1][t * 8]);
            gload16(ga1, &lA[cur ^ 1][t * 8 + 2048]);
#pragma unroll
            for (int c = 0; c < 4; ++c)
                gload16(gb + c * 8, &lB[cur ^ 1][c * 2048 + t * 8]);
            ga0 += BK; ga1 += BK; gb += BK;
        }
        bf16x8 af[4], bfr[8];
#pragma unroll
        for (int i = 0; i < 4; ++i)
            af[i] = *(const bf16x8*)&lA[cur][q4 * 1024 + (wm * 64 + i * 16 + r16) * 8];
#pragma unroll
        for (int i = 0; i < 8; ++i)
            bfr[i] = *(const bf16x8*)&lB[cur][q4 * 2048 + (wn * 128 + i * 16 + r16) * 8];
#pragma unroll
        for (int mi = 0; mi < 4; ++mi)
#pragma unroll
            for (int ni = 0; ni < 8; ++ni)
                acc[mi][ni] = __builtin_amdgcn_mfma_f32_16x16x32_bf16(
                    af[mi], bfr[ni], acc[mi][ni], 0, 0, 0);
        if (it + 1 < nk) __syncthreads();
        cur ^= 1;
    }

#pragma unroll
    for (int mi = 0; mi < 4; ++mi) {
#pragma unroll
        for (int ni = 0; ni < 8; ++ni) {
#pragma unroll
            for (int i = 0; i < 4; ++i) {
                int r = bm + wm * 64 + mi * 16 + q4 * 4 + i;
                int c = bn + wn * 128 + ni * 16 + r16;
                float v = acc[mi][ni][i] + bias[c];
                if (EPI == 1) v += res[(size_t)r * N + c];
                if (EPI == 2) v = gelu_f(v);
                if (OUT32) ((float*)Cp)[(size_t)r * N + c] = v;
                else       ((__bf16*)Cp)[(size_t)r * N + c] = (__bf16)v;
            }
        }
    }
}

// ---------------- Flash attention (causal), HD=64, T=2048, NH=16 ----------------
__global__ __launch_bounds__(256, 4) void attn_kernel(
    const __bf16* __restrict__ qkv, __bf16* __restrict__ attnb)
{
    __shared__ __align__(16) __bf16 lK[8192];    // phys = (d>>3)*1024 + key*8 + (d&7)
    __shared__ __align__(16) __bf16 lV[8192];    // phys = (key>>3)*512 + d*8 + (key&7)
    __shared__ __align__(16) __bf16 lP[4][512];  // per-wave 32-key chunk

    const int t = threadIdx.x, lane = t & 63, w = t >> 6;
    const int q4 = lane >> 4, r16 = lane & 15;
    const int b = blockIdx.y >> 4, h = blockIdx.y & 15;
    const int qt = (blockIdx.x + (blockIdx.y >> 4) * 4) & 15;  // per-CU qt mix
    const int qb = qt * 128;
    const __bf16* Qb = qkv + (size_t)b * 2048 * 3072 + h * 64;
    const __bf16* Kb = Qb + 1024;
    const __bf16* Vb = Qb + 2048;

    bf16x8 qf[2][2];
#pragma unroll
    for (int p = 0; p < 2; ++p) {
        int qrow = qb + p * 64 + w * 16 + r16;
        qf[p][0] = *(const bf16x8*)(Qb + (size_t)qrow * 3072 + q4 * 8);
        qf[p][1] = *(const bf16x8*)(Qb + (size_t)qrow * 3072 + 32 + q4 * 8);
#pragma unroll
        for (int j = 0; j < 8; ++j) {
            qf[p][0][j] = (__bf16)((float)qf[p][0][j] * 0.125f);
            qf[p][1][j] = (__bf16)((float)qf[p][1][j] * 0.125f);
        }
    }

    f32x4 zero4 = {0.f, 0.f, 0.f, 0.f};
    f32x4 o[2][4];
    float rs[2][4];
#pragma unroll
    for (int p = 0; p < 2; ++p)
#pragma unroll
        for (int i = 0; i < 4; ++i) { o[p][i] = zero4; rs[p][i] = 0.f; }

    const int skey = t & 127;
    const int vkc = t >> 6, svd = t & 63;

    for (int kb = 0; kb < qb + 128; kb += 128) {
        __syncthreads();
#pragma unroll
        for (int c = 0; c < 4; ++c)
            gload16(Kb + (size_t)(kb + skey) * 3072 + (c * 2 + (t >> 7)) * 8,
                    &lK[c * 2048 + t * 8]);
#pragma unroll
        for (int c = 0; c < 4; ++c) {
            int kc = c * 4 + vkc;
            bf16x8 vt;
#pragma unroll
            for (int j = 0; j < 8; ++j)
                vt[j] = Vb[(size_t)(kb + kc * 8 + j) * 3072 + svd];
            *(bf16x8*)&lV[kc * 512 + svd * 8] = vt;
        }
        __syncthreads();

#pragma unroll
        for (int p = 0; p < 2; ++p) {
            const int row0 = qb + p * 64 + w * 16 + q4 * 4;
            const bool interior = (kb + 127) <= (qb + p * 64 + w * 16);  // wave-uniform

            f32x4 s[8];
#pragma unroll
            for (int kg = 0; kg < 8; ++kg) {
                bf16x8 kfA = *(const bf16x8*)&lK[q4 * 1024 + (kg * 16 + r16) * 8];
                bf16x8 kfB = *(const bf16x8*)&lK[(4 + q4) * 1024 + (kg * 16 + r16) * 8];
                s[kg] = __builtin_amdgcn_mfma_f32_16x16x32_bf16(qf[p][0], kfA, zero4, 0, 0, 0);
                s[kg] = __builtin_amdgcn_mfma_f32_16x16x32_bf16(qf[p][1], kfB, s[kg], 0, 0, 0);
            }

#pragma unroll
            for (int kg = 0; kg < 8; ++kg)
#pragma unroll
                for (int i = 0; i < 4; ++i) {
                    float e = __expf(fminf(s[kg][i], 75.f));
                    if (!interior && (kb + kg * 16 + r16) > (row0 + i)) e = 0.f;
                    s[kg][i] = e;
                    rs[p][i] += e;
                }

#pragma unroll
            for (int c = 0; c < 4; ++c) {
#pragma unroll
                for (int kh = 0; kh < 2; ++kh)
#pragma unroll
                    for (int i = 0; i < 4; ++i)
                        lP[w][(kh * 2 + (r16 >> 3)) * 128 + (q4 * 4 + i) * 8 + (r16 & 7)] =
                            (__bf16)s[c * 2 + kh][i];
                asm volatile("s_waitcnt lgkmcnt(0)" ::: "memory");
                bf16x8 pf = *(const bf16x8*)&lP[w][q4 * 128 + r16 * 8];
#pragma unroll
                for (int ci = 0; ci < 4; ++ci) {
                    bf16x8 vf = *(const bf16x8*)&lV[(c * 4 + q4) * 512 + (ci * 16 + r16) * 8];
                    o[p][ci] = __builtin_amdgcn_mfma_f32_16x16x32_bf16(pf, vf, o[p][ci], 0, 0, 0);
                }
            }
        }
    }

#pragma unroll
    for (int p = 0; p < 2; ++p) {
#pragma unroll
        for (int off = 8; off; off >>= 1)
#pragma unroll
            for (int i = 0; i < 4; ++i) rs[p][i] += __shfl_xor(rs[p][i], off, 64);
#pragma unroll
        for (int ci = 0; ci < 4; ++ci)
#pragma unroll
            for (int i = 0; i < 4; ++i) {
                int trow = qb + p * 64 + w * 16 + q4 * 4 + i;
                float inv_l = (rs[p][i] > 0.f) ? (1.f / rs[p][i]) : 0.f;
                attnb[(size_t)(b * 2048 + trow) * 1024 + h * 64 + ci * 16 + r16] =
                    (__bf16)(o[p][ci][i] * inv_l);
            }
    }
}

// ---------------- launcher ----------------
extern "C" void kernel_launch(void* const* d_in, const int* in_sizes, int n_in,
                              void* d_out, int out_size, void* d_ws, size_t ws_size,
                              hipStream_t stream)
{
    const float* x      = (const float*)d_in[0];
    const float* ln1_g  = (const float*)d_in[1];
    const float* ln1_b  = (const float*)d_in[2];
    const float* w_qkv  = (const float*)d_in[3];
    const float* b_qkv  = (const float*)d_in[4];
    const float* w_proj = (const float*)d_in[5];
    const float* b_proj = (const float*)d_in[6];
    const float* ln2_g  = (const float*)d_in[7];
    const float* ln2_b  = (const float*)d_in[8];
    const float* w_fc   = (const float*)d_in[9];
    const float* b_fc   = (const float*)d_in[10];
    const float* w_mlp  = (const float*)d_in[11];
    const float* b_mlp  = (const float*)d_in[12];
    float* out = (float*)d_out;

    const size_t MiB = (size_t)1 << 20;
    if (ws_size < 136 * MiB) {
        float v = 1000.f + (float)(ws_size >> 20);
        diag_kernel<<<(out_size + 255) / 256, 256, 0, stream>>>(out, out_size, v);
        return;
    }

    char* ws = (char*)d_ws;
    __bf16* bufA   = (__bf16*)(ws);              // 16 MiB: h -> attnb -> h2
    __bf16* bufB   = (__bf16*)(ws + 16 * MiB);   // 64 MiB: qkvb(48) -> ffb(64)
    float*  x1     = (float*) (ws + 80 * MiB);   // 32 MiB fp32 residual
    __bf16* wqkvT  = (__bf16*)(ws + 112 * MiB);  // 6 MiB
    __bf16* wprojT = (__bf16*)(ws + 118 * MiB);  // 2 MiB
    __bf16* wfcT   = (__bf16*)(ws + 120 * MiB);  // 8 MiB
    __bf16* wmlpT  = (__bf16*)(ws + 128 * MiB);  // 8 MiB

    cvtT_kernel<<<dim3(96, 32),  256, 0, stream>>>(w_qkv,  wqkvT,  1024, 3072);
    cvtT_kernel<<<dim3(32, 32),  256, 0, stream>>>(w_proj, wprojT, 1024, 1024);
    cvtT_kernel<<<dim3(128, 32), 256, 0, stream>>>(w_fc,   wfcT,   1024, 4096);
    cvtT_kernel<<<dim3(32, 128), 256, 0, stream>>>(w_mlp,  wmlpT,  4096, 1024);

    ln_kernel<<<8192, 256, 0, stream>>>(x, ln1_g, ln1_b, bufA, nullptr, nullptr);
    gemm_bt_wide_kernel<0, false><<<dim3(12, 64), 256, 0, stream>>>(
        bufA, wqkvT, b_qkv, nullptr, bufB, 8192, 3072, 1024);
    attn_kernel<<<dim3(16, 64), 256, 0, stream>>>(bufB, bufA);
    gemm_bt_kernel<1, true, 1><<<dim3(8, 64), 256, 0, stream>>>(
        bufA, wprojT, b_proj, x, x1, 8192, 1024, 1024, 1024, 1024);
    // ln2 also pre-inits out = x1 + b_mlp (split-K accumulator base)
    ln_kernel<<<8192, 256, 0, stream>>>(x1, ln2_g, ln2_b, bufA, b_mlp, out);
    gemm_bt_wide_kernel<2, false><<<dim3(16, 64), 256, 0, stream>>>(
        bufA, wfcT, b_fc, nullptr, bufB, 8192, 4096, 1024);
    // mlp proj: split-K=2 (grid.z), fp32 atomicAdd into pre-inited out
    gemm_bt_kernel<3, true, 2><<<dim3(8, 64, 2), 256, 0, stream>>>(
        bufB, wmlpT, b_mlp, nullptr, out, 8192, 1024, 4096, 4096, 4096);
}

// Round 2
// 702.924 us; speedup vs baseline: 1.0570x; 1.0570x over previous
//
#include <hip/hip_runtime.h>
#include <hip/hip_bf16.h>

typedef __bf16 bf16x8 __attribute__((ext_vector_type(8)));
typedef __bf16 bf16x4 __attribute__((ext_vector_type(4)));
typedef float f32x4 __attribute__((ext_vector_type(4)));

#define BM 128
#define BN 128
#define BK 32

__device__ __forceinline__ void gload16(const __bf16* g, __bf16* l) {
    __builtin_amdgcn_global_load_lds((const __attribute__((address_space(1))) void*)g,
                                     (__attribute__((address_space(3))) void*)l, 16, 0, 0);
}

__device__ __forceinline__ float gelu_f(float v) {
    float z = 0.7978845608028654f * (v + 0.044715f * v * v * v);
    float e = __expf(2.f * z);
    return 0.5f * v * (2.f - 2.f / (e + 1.f));  // 0.5*v*(1+tanh(z)), overflow-safe
}

// XCD-chunk swizzle (bijective when nwg%8==0): each XCD gets a contiguous
// chunk of the flat grid, so blocks sharing operand panels co-reside in one L2.
__device__ __forceinline__ int xcd_swizzle(int flat, int nwg) {
    return (flat & 7) * (nwg >> 3) + (flat >> 3);
}

// ---------------- diagnostic fill (fp32 out) ----------------
__global__ __launch_bounds__(256) void diag_kernel(float* out, int n, float v) {
    int i = blockIdx.x * 256 + threadIdx.x;
    if (i < n) out[i] = v;
}

// ---------------- fused fp32->bf16 convert + transpose: in[K,N] -> out[N,K] ----------------
__global__ __launch_bounds__(256) void cvtT_kernel(
    const float* __restrict__ in, __bf16* __restrict__ out, int K, int N)
{
    __shared__ __bf16 tile[32][33];
    int bx = blockIdx.x * 32, by = blockIdx.y * 32;  // bx: n, by: k
    int tx = threadIdx.x & 31, ty = threadIdx.x >> 5;  // 32 x 8
#pragma unroll
    for (int i = 0; i < 32; i += 8)
        tile[ty + i][tx] = (__bf16)in[(size_t)(by + ty + i) * N + bx + tx];
    __syncthreads();
#pragma unroll
    for (int i = 0; i < 32; i += 8)
        out[(size_t)(bx + ty + i) * K + by + tx] = tile[tx][ty + i];
}

// ---------------- LayerNorm: fp32 in, bf16 out; one block per row of 1024 ----------------
__global__ __launch_bounds__(256) void ln_kernel(
    const float* __restrict__ x, const float* __restrict__ g,
    const float* __restrict__ bta, __bf16* __restrict__ out)
{
    const int row = blockIdx.x, t = threadIdx.x;
    const float* xr = x + (size_t)row * 1024;
    float4 xv = ((const float4*)xr)[t];
    float f[4] = {xv.x, xv.y, xv.z, xv.w};
    float s = f[0] + f[1] + f[2] + f[3];
    float ss = f[0]*f[0] + f[1]*f[1] + f[2]*f[2] + f[3]*f[3];
#pragma unroll
    for (int off = 32; off; off >>= 1) {
        s  += __shfl_xor(s, off, 64);
        ss += __shfl_xor(ss, off, 64);
    }
    __shared__ float red[8];
    int lane = t & 63, w = t >> 6;
    if (lane == 0) { red[w] = s; red[4 + w] = ss; }
    __syncthreads();
    s  = red[0] + red[1] + red[2] + red[3];
    ss = red[4] + red[5] + red[6] + red[7];
    float mu = s * (1.f / 1024.f);
    float var = ss * (1.f / 1024.f) - mu * mu;
    float rstd = rsqrtf(fmaxf(var, 0.f) + 1e-5f);
    float4 gv = ((const float4*)g)[t];
    float4 bv = ((const float4*)bta)[t];
    bf16x4 ov;
    ov[0] = (__bf16)((f[0] - mu) * rstd * gv.x + bv.x);
    ov[1] = (__bf16)((f[1] - mu) * rstd * gv.y + bv.y);
    ov[2] = (__bf16)((f[2] - mu) * rstd * gv.z + bv.z);
    ov[3] = (__bf16)((f[3] - mu) * rstd * gv.w + bv.w);
    ((bf16x4*)(out + (size_t)row * 1024))[t] = ov;
}

// ---------------- GEMM 128x128 (m97 + dbuf 2-phase + XCD swizzle) ----------------
// EPI: 0 bias, 1 bias+res(f32), 2 bias+gelu
template <int EPI, bool OUT32>
__global__ __launch_bounds__(256, 4) void gemm_bt_kernel(
    const __bf16* __restrict__ A, const __bf16* __restrict__ BT,
    const float* __restrict__ bias, const float* __restrict__ res,
    void* __restrict__ Cp, int M, int N, int K)
{
    __shared__ __align__(16) __bf16 lA[2][BM * BK];  // phys = kc*1024 + row*8 + j
    __shared__ __align__(16) __bf16 lB[2][BN * BK];
    const int t = threadIdx.x;
    const int lane = t & 63;
    const int wave = t >> 6;
    const int wm = wave >> 1, wn = wave & 1;
    const int q4 = lane >> 4, r16 = lane & 15;
    // XCD swizzle: columns fastest within each XCD's contiguous chunk
    const int nwg = gridDim.x * gridDim.y;
    const int nf = xcd_swizzle(blockIdx.y * gridDim.x + blockIdx.x, nwg);
    const int bm = (nf / gridDim.x) * BM, bn = (nf % gridDim.x) * BN;

    const int srow = t & 127;
    const int skc = t >> 7;
    const __bf16* ga0 = A + (size_t)(bm + srow) * K + skc * 8;
    const __bf16* ga1 = ga0 + 16;
    const __bf16* gb0 = BT + (size_t)(bn + srow) * K + skc * 8;
    const __bf16* gb1 = gb0 + 16;

    f32x4 acc[4][4];
    f32x4 zero4 = {0.f, 0.f, 0.f, 0.f};
#pragma unroll
    for (int mi = 0; mi < 4; ++mi)
#pragma unroll
        for (int ni = 0; ni < 4; ++ni) acc[mi][ni] = zero4;

    // prologue: stage tile 0 into buf 0
    gload16(ga0, &lA[0][t * 8]);
    gload16(ga1, &lA[0][t * 8 + 2048]);
    gload16(gb0, &lB[0][t * 8]);
    gload16(gb1, &lB[0][t * 8 + 2048]);
    ga0 += BK; ga1 += BK; gb0 += BK; gb1 += BK;
    __syncthreads();  // drains vmcnt, tile 0 visible

    const int nk = K / BK;
    int cur = 0;
    for (int it = 0; it < nk; ++it) {
        if (it + 1 < nk) {  // issue next tile's loads BEFORE computing current
            gload16(ga0, &lA[cur ^ 1][t * 8]);
            gload16(ga1, &lA[cur ^ 1][t * 8 + 2048]);
            gload16(gb0, &lB[cur ^ 1][t * 8]);
            gload16(gb1, &lB[cur ^ 1][t * 8 + 2048]);
            ga0 += BK; ga1 += BK; gb0 += BK; gb1 += BK;
        }
        bf16x8 af[4], bfr[4];
#pragma unroll
        for (int i = 0; i < 4; ++i)
            af[i] = *(const bf16x8*)&lA[cur][q4 * 1024 + (wm * 64 + i * 16 + r16) * 8];
#pragma unroll
        for (int i = 0; i < 4; ++i)
            bfr[i] = *(const bf16x8*)&lB[cur][q4 * 1024 + (wn * 64 + i * 16 + r16) * 8];
#pragma unroll
        for (int mi = 0; mi < 4; ++mi)
#pragma unroll
            for (int ni = 0; ni < 4; ++ni)
                acc[mi][ni] = __builtin_amdgcn_mfma_f32_16x16x32_bf16(
                    af[mi], bfr[ni], acc[mi][ni], 0, 0, 0);
        if (it + 1 < nk) __syncthreads();  // next tile staged + cur reads done
        cur ^= 1;
    }

#pragma unroll
    for (int mi = 0; mi < 4; ++mi) {
#pragma unroll
        for (int ni = 0; ni < 4; ++ni) {
#pragma unroll
            for (int i = 0; i < 4; ++i) {
                int r = bm + wm * 64 + mi * 16 + q4 * 4 + i;
                int c = bn + wn * 64 + ni * 16 + r16;
                float v = acc[mi][ni][i] + bias[c];
                if (EPI == 1) v += res[(size_t)r * N + c];
                if (EPI == 2) v = gelu_f(v);
                if (OUT32) ((float*)Cp)[(size_t)r * N + c] = v;
                else       ((__bf16*)Cp)[(size_t)r * N + c] = (__bf16)v;
            }
        }
    }
}

// ---------------- GEMM 128x256 wide (dbuf 2-phase + XCD swizzle): qkv, fc ----------------
template <int EPI, bool OUT32>
__global__ __launch_bounds__(256, 2) void gemm_bt_wide_kernel(
    const __bf16* __restrict__ A, const __bf16* __restrict__ BT,
    const float* __restrict__ bias, const float* __restrict__ res,
    void* __restrict__ Cp, int M, int N, int K)
{
    __shared__ __align__(16) __bf16 lA[2][128 * BK];  // phys = kc*1024 + row*8 + j
    __shared__ __align__(16) __bf16 lB[2][256 * BK];  // phys = kc*2048 + row*8 + j
    const int t = threadIdx.x;
    const int lane = t & 63;
    const int wave = t >> 6;
    const int wm = wave >> 1, wn = wave & 1;
    const int q4 = lane >> 4, r16 = lane & 15;
    const int nwg = gridDim.x * gridDim.y;
    const int nf = xcd_swizzle(blockIdx.y * gridDim.x + blockIdx.x, nwg);
    const int bm = (nf / gridDim.x) * 128, bn = (nf % gridDim.x) * 256;

    const int srow = t & 127;
    const int skc = t >> 7;
    const __bf16* ga0 = A + (size_t)(bm + srow) * K + skc * 8;
    const __bf16* ga1 = ga0 + 16;
    const __bf16* gb  = BT + (size_t)(bn + t) * K;

    f32x4 acc[4][8];
    f32x4 zero4 = {0.f, 0.f, 0.f, 0.f};
#pragma unroll
    for (int mi = 0; mi < 4; ++mi)
#pragma unroll
        for (int ni = 0; ni < 8; ++ni) acc[mi][ni] = zero4;

    // prologue: stage tile 0 into buf 0
    gload16(ga0, &lA[0][t * 8]);
    gload16(ga1, &lA[0][t * 8 + 2048]);
#pragma unroll
    for (int c = 0; c < 4; ++c)
        gload16(gb + c * 8, &lB[0][c * 2048 + t * 8]);
    ga0 += BK; ga1 += BK; gb += BK;
    __syncthreads();

    const int nk = K / BK;
    int cur = 0;
    for (int it = 0; it < nk; ++it) {
        if (it + 1 < nk) {
            gload16(ga0, &lA[cur ^ 1][t * 8]);
            gload16(ga1, &lA[cur ^ 1][t * 8 + 2048]);
#pragma unroll
            for (int c = 0; c < 4; ++c)
                gload16(gb + c * 8, &lB[cur ^ 1][c * 2048 + t * 8]);
            ga0 += BK; ga1 += BK; gb += BK;
        }
        bf16x8 af[4], bfr[8];
#pragma unroll
        for (int i = 0; i < 4; ++i)
            af[i] = *(const bf16x8*)&lA[cur][q4 * 1024 + (wm * 64 + i * 16 + r16) * 8];
#pragma unroll
        for (int i = 0; i < 8; ++i)
            bfr[i] = *(const bf16x8*)&lB[cur][q4 * 2048 + (wn * 128 + i * 16 + r16) * 8];
#pragma unroll
        for (int mi = 0; mi < 4; ++mi)
#pragma unroll
            for (int ni = 0; ni < 8; ++ni)
                acc[mi][ni] = __builtin_amdgcn_mfma_f32_16x16x32_bf16(
                    af[mi], bfr[ni], acc[mi][ni], 0, 0, 0);
        if (it + 1 < nk) __syncthreads();
        cur ^= 1;
    }

#pragma unroll
    for (int mi = 0; mi < 4; ++mi) {
#pragma unroll
        for (int ni = 0; ni < 8; ++ni) {
#pragma unroll
            for (int i = 0; i < 4; ++i) {
                int r = bm + wm * 64 + mi * 16 + q4 * 4 + i;
                int c = bn + wn * 128 + ni * 16 + r16;
                float v = acc[mi][ni][i] + bias[c];
                if (EPI == 1) v += res[(size_t)r * N + c];
                if (EPI == 2) v = gelu_f(v);
                if (OUT32) ((float*)Cp)[(size_t)r * N + c] = v;
                else       ((__bf16*)Cp)[(size_t)r * N + c] = (__bf16)v;
            }
        }
    }
}

// ---------------- Flash attention (causal), HD=64, T=2048, NH=16 ----------------
__global__ __launch_bounds__(256, 4) void attn_kernel(
    const __bf16* __restrict__ qkv, __bf16* __restrict__ attnb)
{
    __shared__ __align__(16) __bf16 lK[8192];    // phys = (d>>3)*1024 + key*8 + (d&7)
    __shared__ __align__(16) __bf16 lV[8192];    // phys = (key>>3)*512 + d*8 + (key&7)
    __shared__ __align__(16) __bf16 lP[4][512];  // per-wave 32-key chunk

    const int t = threadIdx.x, lane = t & 63, w = t >> 6;
    const int q4 = lane >> 4, r16 = lane & 15;
    // XCD swizzle: each XCD owns 8 consecutive (b,h) pairs across all 16 q-tiles,
    // so the K/V panels it streams stay resident in its own L2.
    const int nf = xcd_swizzle(blockIdx.y * 16 + blockIdx.x, 1024);
    const int qt = nf & 15;
    const int bh = nf >> 4;
    const int b = bh >> 4, h = bh & 15;
    const int qb = qt * 128;
    const __bf16* Qb = qkv + (size_t)b * 2048 * 3072 + h * 64;
    const __bf16* Kb = Qb + 1024;
    const __bf16* Vb = Qb + 2048;

    bf16x8 qf[2][2];
#pragma unroll
    for (int p = 0; p < 2; ++p) {
        int qrow = qb + p * 64 + w * 16 + r16;
        qf[p][0] = *(const bf16x8*)(Qb + (size_t)qrow * 3072 + q4 * 8);
        qf[p][1] = *(const bf16x8*)(Qb + (size_t)qrow * 3072 + 32 + q4 * 8);
#pragma unroll
        for (int j = 0; j < 8; ++j) {
            qf[p][0][j] = (__bf16)((float)qf[p][0][j] * 0.125f);
            qf[p][1][j] = (__bf16)((float)qf[p][1][j] * 0.125f);
        }
    }

    f32x4 zero4 = {0.f, 0.f, 0.f, 0.f};
    f32x4 o[2][4];
    float rs[2][4];
#pragma unroll
    for (int p = 0; p < 2; ++p)
#pragma unroll
        for (int i = 0; i < 4; ++i) { o[p][i] = zero4; rs[p][i] = 0.f; }

    const int skey = t & 127;
    const int vkc = t >> 6, svd = t & 63;

    for (int kb = 0; kb < qb + 128; kb += 128) {
        __syncthreads();
#pragma unroll
        for (int c = 0; c < 4; ++c)
            gload16(Kb + (size_t)(kb + skey) * 3072 + (c * 2 + (t >> 7)) * 8,
                    &lK[c * 2048 + t * 8]);
#pragma unroll
        for (int c = 0; c < 4; ++c) {
            int kc = c * 4 + vkc;
            bf16x8 vt;
#pragma unroll
            for (int j = 0; j < 8; ++j)
                vt[j] = Vb[(size_t)(kb + kc * 8 + j) * 3072 + svd];
            *(bf16x8*)&lV[kc * 512 + svd * 8] = vt;
        }
        __syncthreads();

#pragma unroll
        for (int p = 0; p < 2; ++p) {
            const int row0 = qb + p * 64 + w * 16 + q4 * 4;
            const bool interior = (kb + 127) <= (qb + p * 64 + w * 16);  // wave-uniform

            f32x4 s[8];
#pragma unroll
            for (int kg = 0; kg < 8; ++kg) {
                bf16x8 kfA = *(const bf16x8*)&lK[q4 * 1024 + (kg * 16 + r16) * 8];
                bf16x8 kfB = *(const bf16x8*)&lK[(4 + q4) * 1024 + (kg * 16 + r16) * 8];
                s[kg] = __builtin_amdgcn_mfma_f32_16x16x32_bf16(qf[p][0], kfA, zero4, 0, 0, 0);
                s[kg] = __builtin_amdgcn_mfma_f32_16x16x32_bf16(qf[p][1], kfB, s[kg], 0, 0, 0);
            }

#pragma unroll
            for (int kg = 0; kg < 8; ++kg)
#pragma unroll
                for (int i = 0; i < 4; ++i) {
                    float e = __expf(fminf(s[kg][i], 75.f));
                    if (!interior && (kb + kg * 16 + r16) > (row0 + i)) e = 0.f;
                    s[kg][i] = e;
                    rs[p][i] += e;
                }

#pragma unroll
            for (int c = 0; c < 4; ++c) {
#pragma unroll
                for (int kh = 0; kh < 2; ++kh)
#pragma unroll
                    for (int i = 0; i < 4; ++i)
                        lP[w][(kh * 2 + (r16 >> 3)) * 128 + (q4 * 4 + i) * 8 + (r16 & 7)] =
                            (__bf16)s[c * 2 + kh][i];
                asm volatile("s_waitcnt lgkmcnt(0)" ::: "memory");
                bf16x8 pf = *(const bf16x8*)&lP[w][q4 * 128 + r16 * 8];
#pragma unroll
                for (int ci = 0; ci < 4; ++ci) {
                    bf16x8 vf = *(const bf16x8*)&lV[(c * 4 + q4) * 512 + (ci * 16 + r16) * 8];
                    o[p][ci] = __builtin_amdgcn_mfma_f32_16x16x32_bf16(pf, vf, o[p][ci], 0, 0, 0);
                }
            }
        }
    }

#pragma unroll
    for (int p = 0; p < 2; ++p) {
#pragma unroll
        for (int off = 8; off; off >>= 1)
#pragma unroll
            for (int i = 0; i < 4; ++i) rs[p][i] += __shfl_xor(rs[p][i], off, 64);
#pragma unroll
        for (int ci = 0; ci < 4; ++ci)
#pragma unroll
            for (int i = 0; i < 4; ++i) {
                int trow = qb + p * 64 + w * 16 + q4 * 4 + i;
                float inv_l = (rs[p][i] > 0.f) ? (1.f / rs[p][i]) : 0.f;
                attnb[(size_t)(b * 2048 + trow) * 1024 + h * 64 + ci * 16 + r16] =
                    (__bf16)(o[p][ci][i] * inv_l);
            }
    }
}

// ---------------- launcher ----------------
extern "C" void kernel_launch(void* const* d_in, const int* in_sizes, int n_in,
                              void* d_out, int out_size, void* d_ws, size_t ws_size,
                              hipStream_t stream)
{
    const float* x      = (const float*)d_in[0];
    const float* ln1_g  = (const float*)d_in[1];
    const float* ln1_b  = (const float*)d_in[2];
    const float* w_qkv  = (const float*)d_in[3];
    const float* b_qkv  = (const float*)d_in[4];
    const float* w_proj = (const float*)d_in[5];
    const float* b_proj = (const float*)d_in[6];
    const float* ln2_g  = (const float*)d_in[7];
    const float* ln2_b  = (const float*)d_in[8];
    const float* w_fc   = (const float*)d_in[9];
    const float* b_fc   = (const float*)d_in[10];
    const float* w_mlp  = (const float*)d_in[11];
    const float* b_mlp  = (const float*)d_in[12];
    float* out = (float*)d_out;

    const size_t MiB = (size_t)1 << 20;
    if (ws_size < 136 * MiB) {
        float v = 1000.f + (float)(ws_size >> 20);
        diag_kernel<<<(out_size + 255) / 256, 256, 0, stream>>>(out, out_size, v);
        return;
    }

    char* ws = (char*)d_ws;
    __bf16* bufA   = (__bf16*)(ws);              // 16 MiB: h -> attnb -> h2
    __bf16* bufB   = (__bf16*)(ws + 16 * MiB);   // 64 MiB: qkvb(48) -> ffb(64)
    float*  x1     = (float*) (ws + 80 * MiB);   // 32 MiB fp32 residual
    __bf16* wqkvT  = (__bf16*)(ws + 112 * MiB);  // 6 MiB
    __bf16* wprojT = (__bf16*)(ws + 118 * MiB);  // 2 MiB
    __bf16* wfcT   = (__bf16*)(ws + 120 * MiB);  // 8 MiB
    __bf16* wmlpT  = (__bf16*)(ws + 128 * MiB);  // 8 MiB

    cvtT_kernel<<<dim3(96, 32),  256, 0, stream>>>(w_qkv,  wqkvT,  1024, 3072);
    cvtT_kernel<<<dim3(32, 32),  256, 0, stream>>>(w_proj, wprojT, 1024, 1024);
    cvtT_kernel<<<dim3(128, 32), 256, 0, stream>>>(w_fc,   wfcT,   1024, 4096);
    cvtT_kernel<<<dim3(32, 128), 256, 0, stream>>>(w_mlp,  wmlpT,  4096, 1024);

    ln_kernel<<<8192, 256, 0, stream>>>(x, ln1_g, ln1_b, bufA);
    gemm_bt_wide_kernel<0, false><<<dim3(12, 64), 256, 0, stream>>>(
        bufA, wqkvT, b_qkv, nullptr, bufB, 8192, 3072, 1024);
    attn_kernel<<<dim3(16, 64), 256, 0, stream>>>(bufB, bufA);
    gemm_bt_kernel<1, true><<<dim3(8, 64), 256, 0, stream>>>(
        bufA, wprojT, b_proj, x, x1, 8192, 1024, 1024);
    ln_kernel<<<8192, 256, 0, stream>>>(x1, ln2_g, ln2_b, bufA);
    gemm_bt_wide_kernel<2, false><<<dim3(16, 64), 256, 0, stream>>>(
        bufA, wfcT, b_fc, nullptr, bufB, 8192, 4096, 1024);
    gemm_bt_kernel<1, true><<<dim3(8, 64), 256, 0, stream>>>(
        bufB, wmlpT, b_mlp, x1, out, 8192, 1024, 4096);
}